// Round 9
// baseline (383.832 us; speedup 1.0000x reference)
//
#include <hip/hip_runtime.h>
#include <hip/hip_bf16.h>

#define BB 16
#define SS 2048
#define DD 64
#define NT_TILES (SS / 128)     // 16 k-tiles per batch
#define TILE_BYTES 16384        // one prepacked tile image (K or V^T), bf16 swizzled
#define KVBUF 32768             // one KV buffer: K 16K (4 kh slices) + V 16K
#define MBUF  32768             // one M buffer: 64 rows x 512B (block-cooperative)

typedef __attribute__((ext_vector_type(8)))  unsigned short ushort8;
typedef __attribute__((ext_vector_type(8)))  __bf16 bf16x8;
typedef __attribute__((ext_vector_type(16))) float f32x16;
typedef __attribute__((ext_vector_type(4)))  unsigned int uint4v;

static __device__ __forceinline__ unsigned short f2bf(float x) {
    return __builtin_bit_cast(unsigned short, __float2bfloat16(x));
}
static __device__ __forceinline__ unsigned pk2(float a, float b) {
    return (unsigned)f2bf(a) | ((unsigned)f2bf(b) << 16);
}
union F4 { float4 v; float a[4]; };

// width-16 async global->LDS copy. LDS dest = wave-uniform base + lane*16;
// global src is per-lane. Fire-and-forget (vmcnt domain only).
#define GLDS16(src, dst) __builtin_amdgcn_global_load_lds(                 \
    (const __attribute__((address_space(1))) unsigned int*)(src),          \
    (__attribute__((address_space(3))) unsigned int*)(dst), 16, 0, 0)

// ---------------------------------------------------------------------------
// KV pre-pack (unchanged, verified r1-r8): fp32 K,V -> bf16 swizzled 16KB
// tile images in workspace. One block per (k-tile, batch).
// ---------------------------------------------------------------------------
__global__ __launch_bounds__(256)
void prepack_kernel(const float* __restrict__ K, const float* __restrict__ V,
                    char* __restrict__ wsK, char* __restrict__ wsV) {
    __shared__ __align__(16) char smem[32768];
    char* Ks = smem;
    char* Vs = smem + 16384;
    const int t  = threadIdx.x;
    const int kt = blockIdx.x;
    const int b  = blockIdx.y;
    const float* Kg = K + (size_t)b * SS * DD;
    const float* Vg = V + (size_t)b * SS * DD;

    #pragma unroll
    for (int j = 0; j < 4; j++) {
        const int idx = 2 * t + 512 * j;
        const int row = idx >> 4;
        const int g   = (idx & 15) >> 1;
        const float* src = Kg + (size_t)(kt * 128) * DD + (size_t)idx * 4;
        F4 fa, fb; fa.v = *(const float4*)src; fb.v = *(const float4*)(src + 4);
        ushort8 u;
        #pragma unroll
        for (int e = 0; e < 4; e++) { u[e] = f2bf(fa.a[e]); u[e + 4] = f2bf(fb.a[e]); }
        *(ushort8*)(Ks + row * 128 + ((g ^ (row & 7)) * 16)) = u;
    }
    {
        const int d0v = (t & 15) * 4;
        const int kkb = (t >> 4) * 4;
        #pragma unroll
        for (int it2 = 0; it2 < 2; it2++) {
            const int kk = kkb + 64 * it2;
            const float* src = Vg + (size_t)(kt * 128 + kk) * DD + d0v;
            F4 r0, r1, r2, r3;
            r0.v = *(const float4*)(src);
            r1.v = *(const float4*)(src + DD);
            r2.v = *(const float4*)(src + 2 * DD);
            r3.v = *(const float4*)(src + 3 * DD);
            #pragma unroll
            for (int e = 0; e < 4; e++) {
                const int d = d0v + e;
                const uint2 wv = make_uint2(pk2(r0.a[e], r1.a[e]), pk2(r2.a[e], r3.a[e]));
                *(uint2*)(Vs + d * 256 + (((kk >> 3) ^ (d & 15)) * 16) + (kk & 7) * 2) = wv;
            }
        }
    }
    __syncthreads();
    char* dK = wsK + (size_t)(b * NT_TILES + kt) * TILE_BYTES;
    char* dV = wsV + (size_t)(b * NT_TILES + kt) * TILE_BYTES;
    #pragma unroll
    for (int j = 0; j < 4; j++) {
        *(float4*)(dK + t * 16 + j * 4096) = *(const float4*)(Ks + t * 16 + j * 4096);
        *(float4*)(dV + t * 16 + j * 4096) = *(const float4*)(Vs + t * 16 + j * 4096);
    }
}

// ---------------------------------------------------------------------------
// Main kernel (r7/r8 structure: 8 waves = 2 qs x 4 kh, shared KV dbuf +
// M tbuf, counted vmcnt(4) + raw s_barrier lockstep, zero drains).
// r8 post-mortem: body = 4875cy vs 3200cy BW floor; LDS conflicts were slack
// (fix changed nothing) -> mask stream runs at ~65% of achievable BW because
// each glds read 8 scattered 128B runs. Fix: BLOCK-COOPERATIVE full-row mask
// staging. Wave w stages whole rows 8w..8w+7 (512B wide): one glds = two
// contiguous 512B runs (4x granularity). Waves then ds_read their column
// slice from the shared buffer (wait->barrier makes cross-wave data visible,
// same argument as shared KV, proven r7/r8). LDS pitch 512B would be 32-way
// conflicted on the column read -> granule XOR ^(row&7): pre-swizzled global
// SOURCE (linear glds dest, rule 21) + matching XOR on the read. Involution:
// LDS granule G of row r holds global granule G^(r&7); read fetches
// (8kh+2g+half)^(l31&7) = the same mt[g] words as r8. 8 lanes cover all 32
// banks, uniform 8 dwords/bank. Byte counts, glds counts, vmcnt math, issue
// order: unchanged.
// ---------------------------------------------------------------------------
__global__ __launch_bounds__(512, 1)
void sdpa_mfma_kernel(const float* __restrict__ Q, const char* __restrict__ wsK,
                      const char* __restrict__ wsV, const unsigned int* __restrict__ M,
                      float* __restrict__ O) {
    __shared__ __align__(16) char smem[2 * KVBUF + 3 * MBUF];   // 160 KB exactly
    char* Qs = smem;                         // 8 KB, pre-loop only (in KV buf0)
    char* const Mbase = smem + 2 * KVBUF;    // M buffers
    float* red  = (float*)smem;              // epilogue partials (48 KB)
    float* denx = (float*)(smem + 49152);    // epilogue den exchange (1 KB)

    const int t    = threadIdx.x;
    const int lane = t & 63;
    const int l31  = lane & 31;
    const int half = lane >> 5;
    const int w    = t >> 6;          // wave id 0..7
    const int kh   = w & 3;           // k-chunk 32*kh of the 128-tile
    const int qs   = w >> 2;          // q-subtile (0: rows q0.., 1: rows q0+32..)
    const int b    = blockIdx.y;
    const int q0   = blockIdx.x * 64;
    const int q0v  = q0 + 32 * qs;

    // ---- stage Q (64 rows, pre-scaled by 1/temperature), swizzled bf16 ----
    {
        const int sr = t >> 3, sc = t & 7;   // 512 thr -> 64 rows x 8 chunks
        const float* src = Q + ((size_t)b * SS + q0 + sr) * DD + sc * 8;
        F4 f0, f1; f0.v = *(const float4*)src; f1.v = *(const float4*)(src + 4);
        ushort8 u;
        #pragma unroll
        for (int e = 0; e < 4; e++) {
            u[e]     = f2bf(f0.a[e] * 0.125f);
            u[e + 4] = f2bf(f1.a[e] * 0.125f);
        }
        *(ushort8*)(Qs + sr * 128 + ((sc ^ (sr & 7)) * 16)) = u;
    }
    __syncthreads();

    const int qrow = l31;
    const int r7   = l31 & 7;
    bf16x8 bq[4];
    #pragma unroll
    for (int dc = 0; dc < 4; dc++)
        bq[dc] = __builtin_bit_cast(bf16x8, *(const ushort8*)(
            Qs + (32 * qs + qrow) * 128 + (((2 * dc + half) ^ r7) * 16)));
    __syncthreads();   // all bq reads done before prologue stages overwrite Qs

    f32x16 On0, On1;
    #pragma unroll
    for (int i = 0; i < 16; i++) { On0[i] = 0.f; On1[i] = 0.f; }
    float den0 = 0.f, den1 = 0.f;

    const char* tKbase = wsK + (size_t)b * NT_TILES * TILE_BYTES;
    const char* tVbase = wsV + (size_t)b * NT_TILES * TILE_BYTES;

    // mask staging src (block-cooperative full-row): wave w, glds j covers
    // rows q0+8w+2j+(lane>>5), full 512B width; lane reads 16B at granule
    // (lane&31)^(2j+(lane>>5))  [= ^(row&7), source pre-swizzle]
    const unsigned int* Mwrow = M + (size_t)b * SS * SS
                                  + (size_t)(q0 + 8 * w + half) * SS;
    const int g32 = l31;     // global granule base within the row (lane&31)
    // V staging src per-lane offset (r6-verified granule extract + r8 bank swz)
    const int voff = ((lane >> 2) * 256)
                   + ((kh ^ ((lane >> 4) & 3)) * 64)
                   + ((((lane & 3) ^ ((lane >> 3) & 3) ^ ((lane >> 2) & 3)) * 16));

    auto stage_kv = [&](int bufn, int kt) {
        char* kvb = smem + bufn * KVBUF;
        if (qs == 0) {      // wave-uniform branch: qs=0 waves stage K slice kh
            const char* tK = tKbase + (size_t)kt * TILE_BYTES + 32 * kh * 128;
            #pragma unroll
            for (int j = 0; j < 4; j++)
                GLDS16(tK + j * 1024 + lane * 16, kvb + kh * 4096 + j * 1024);
        } else {            // qs=1 waves stage V slice kh (granule extract)
            const char* tV = tVbase + (size_t)kt * TILE_BYTES;
            #pragma unroll
            for (int j = 0; j < 4; j++)
                GLDS16(tV + j * 4096 + voff, kvb + 16384 + kh * 4096 + j * 1024);
        }
    };
    auto stage_m = [&](int bufn, int kt) {
        char* mb = Mbase + bufn * MBUF + w * 4096;   // rows 8w.., 512B pitch
        const unsigned int* ms = Mwrow + (size_t)kt * 128;
        #pragma unroll
        for (int j = 0; j < 4; j++)                  // 2 rows x 512B per glds
            GLDS16(ms + (size_t)(2 * j) * SS + 4 * (g32 ^ (2 * j + half)),
                   mb + j * 1024);
    };

    // prologue: KV(0), M(0), M(1) in flight (12 glds)
    stage_kv(0, 0);
    stage_m(0, 0);
    stage_m(1, 1);

    #pragma unroll 1
    for (int kt = 0; kt < NT_TILES; ++kt) {
        // 1. counted wait: newest 4 = next M batch; retires M(kt) + KV(kt).
        asm volatile("s_waitcnt vmcnt(4)" ::: "memory");
        __builtin_amdgcn_sched_barrier(0);
        // 2. raw barrier (no drain): kt data visible cross-wave, kt-1 bufs free
        __builtin_amdgcn_s_barrier();
        // 3./4. stages (dead clamped tails target non-live buffers)
        const int kKV = (kt + 1 < NT_TILES) ? kt + 1 : NT_TILES - 1;
        const int kM  = (kt + 2 < NT_TILES) ? kt + 2 : NT_TILES - 1;
        stage_kv((kt + 1) & 1, kKV);
        stage_m((kt + 2) % 3, kM);

        // 5. consume tile kt
        const char* kvb = smem + (kt & 1) * KVBUF;
        const char* mbuf = Mbase + (kt % 3) * MBUF;

        bf16x8 ak[4];
        #pragma unroll
        for (int dc = 0; dc < 4; dc++)
            ak[dc] = __builtin_bit_cast(bf16x8, *(const ushort8*)(
                kvb + kh * 4096 + l31 * 128 + (((2 * dc + half) ^ r7) * 16)));
        // mask words: row 32qs+l31, global granule 8kh+2g+half, LDS granule
        // XOR (l31&7). Same mt[g] <-> col 32kh+4half+8g+e mapping as r8.
        uint4v mt[4];
        #pragma unroll
        for (int g = 0; g < 4; g++)
            mt[g] = *(const uint4v*)(mbuf + (32 * qs + l31) * 512 +
                                     16 * ((8 * kh + 2 * g + half) ^ r7));
        bf16x8 av[2][2];
        #pragma unroll
        for (int s2 = 0; s2 < 2; s2++)
            #pragma unroll
            for (int dc = 0; dc < 2; dc++) {
                const int vrow = 32 * dc + l31;
                av[s2][dc] = __builtin_bit_cast(bf16x8, *(const ushort8*)(
                    kvb + 16384 + kh * 4096 + vrow * 64 +
                    (((2 * s2 + half) ^ ((l31 >> 1) & 3)) * 16)));
            }

        // QK^T: S^T tile [32k x 32q]
        f32x16 S;
        #pragma unroll
        for (int i = 0; i < 16; i++) S[i] = 0.f;
        #pragma unroll
        for (int dc = 0; dc < 4; dc++)
            S = __builtin_amdgcn_mfma_f32_32x32x16_bf16(ak[dc], bq[dc], S, 0, 0, 0);

        // mask + exp + denominator (C row = e + 8g + 4half)
        float p[16];
        #pragma unroll
        for (int g = 0; g < 4; g++) {
            #pragma unroll
            for (int e = 0; e < 4; e++) {
                const float ev = __expf(S[4 * g + e]);
                const float pv = mt[g][e] ? 1.0f : ev;
                p[4 * g + e] = pv;
                if (g & 1) den1 += pv; else den0 += pv;
            }
        }

        // P*V: B-operand frags via shfl_xor(32), 2 ksubs (r0-proven)
        #pragma unroll
        for (int s2 = 0; s2 < 2; s2++) {
            const unsigned o0 = pk2(p[8 * s2 + 0], p[8 * s2 + 1]);
            const unsigned o1 = pk2(p[8 * s2 + 2], p[8 * s2 + 3]);
            const unsigned o2 = pk2(p[8 * s2 + 4], p[8 * s2 + 5]);
            const unsigned o3 = pk2(p[8 * s2 + 6], p[8 * s2 + 7]);
            const unsigned s0 = half ? o0 : o2;
            const unsigned s1 = half ? o1 : o3;
            const unsigned r0 = (unsigned)__shfl_xor((int)s0, 32, 64);
            const unsigned r1 = (unsigned)__shfl_xor((int)s1, 32, 64);
            uint4 bu;
            bu.x = half ? r0 : o0;
            bu.y = half ? r1 : o1;
            bu.z = half ? o2 : r0;
            bu.w = half ? o3 : r1;
            const bf16x8 bp = __builtin_bit_cast(bf16x8, bu);
            On0 = __builtin_amdgcn_mfma_f32_32x32x16_bf16(av[s2][0], bp, On0, 0, 0, 0);
            On1 = __builtin_amdgcn_mfma_f32_32x32x16_bf16(av[s2][1], bp, On1, 0, 0, 0);
        }
    }

    // ---- epilogue: lane halves, then 4-way kh reduction per qs group ----
    const float den_acc = den0 + den1;
    const float den_tot = den_acc + __shfl_xor(den_acc, 32, 64);

    __syncthreads();   // full drain (incl. dead tail stages); bufs -> red/denx
    if (kh != 0) {
        #pragma unroll
        for (int dc = 0; dc < 2; dc++)
            #pragma unroll
            for (int g = 0; g < 4; g++) {
                const f32x16& Oc = dc ? On1 : On0;
                float4 st;
                st.x = Oc[4 * g + 0]; st.y = Oc[4 * g + 1];
                st.z = Oc[4 * g + 2]; st.w = Oc[4 * g + 3];
                *(float4*)((char*)red + qs * 24576 + (kh - 1) * 8192 +
                           (dc * 4 + g) * 1024 + lane * 16) = st;
            }
        if (lane < 32) denx[w * 32 + l31] = den_tot;
    }
    __syncthreads();
    if (kh == 0) {
        const float inv = 1.0f / (den_tot + denx[(qs * 4 + 1) * 32 + l31]
                                          + denx[(qs * 4 + 2) * 32 + l31]
                                          + denx[(qs * 4 + 3) * 32 + l31]);
        float* Og = O + ((size_t)b * SS + q0v + qrow) * DD;
        #pragma unroll
        for (int dc = 0; dc < 2; dc++)
            #pragma unroll
            for (int g = 0; g < 4; g++) {
                const f32x16& Oc = dc ? On1 : On0;
                float4 st;
                st.x = Oc[4 * g + 0]; st.y = Oc[4 * g + 1];
                st.z = Oc[4 * g + 2]; st.w = Oc[4 * g + 3];
                #pragma unroll
                for (int w2 = 0; w2 < 3; w2++) {
                    const float4 pr = *(const float4*)((char*)red + qs * 24576 +
                                        w2 * 8192 + (dc * 4 + g) * 1024 + lane * 16);
                    st.x += pr.x; st.y += pr.y; st.z += pr.z; st.w += pr.w;
                }
                st.x *= inv; st.y *= inv; st.z *= inv; st.w *= inv;
                // d = e + 8g + 4half + 32dc  (C-row formula)
                *(float4*)(Og + 32 * dc + 8 * g + 4 * half) = st;
            }
    }
}

extern "C" void kernel_launch(void* const* d_in, const int* in_sizes, int n_in,
                              void* d_out, int out_size, void* d_ws, size_t ws_size,
                              hipStream_t stream) {
    const float* q = (const float*)d_in[0];
    const float* k = (const float*)d_in[1];
    const float* v = (const float*)d_in[2];
    const unsigned int* m = (const unsigned int*)d_in[3];
    float* out = (float*)d_out;

    // workspace: 4 MB K images + 4 MB V images (bf16, swizzled tile layout)
    char* wsK = (char*)d_ws;
    char* wsV = wsK + (size_t)BB * NT_TILES * TILE_BYTES;

    dim3 pgrid(NT_TILES, BB);           // 256 blocks
    prepack_kernel<<<pgrid, 256, 0, stream>>>(k, v, wsK, wsV);

    dim3 grid(SS / 64, BB);             // 512 blocks x 512 thr -> 1/CU, 2 rounds
    sdpa_mfma_kernel<<<grid, 512, 0, stream>>>(q, wsK, wsV, m, out);
}

// Round 12
// 380.978 us; speedup vs baseline: 1.0075x; 1.0075x over previous
//
#include <hip/hip_runtime.h>
#include <hip/hip_bf16.h>

#define BB 16
#define SS 2048
#define DD 64
#define NT_TILES (SS / 128)     // 16 k-tiles per batch
#define TILE_BYTES 16384        // one prepacked tile image (K or V^T), bf16 swizzled
#define KVBUF 32768             // one KV buffer: K 16K (4 kh slices) + V 16K
#define MBUF  32768             // one M buffer: 8 waves x 4KB

typedef __attribute__((ext_vector_type(8)))  unsigned short ushort8;
typedef __attribute__((ext_vector_type(8)))  __bf16 bf16x8;
typedef __attribute__((ext_vector_type(16))) float f32x16;
typedef __attribute__((ext_vector_type(4)))  unsigned int uint4v;

static __device__ __forceinline__ unsigned short f2bf(float x) {
    return __builtin_bit_cast(unsigned short, __float2bfloat16(x));
}
static __device__ __forceinline__ unsigned pk2(float a, float b) {
    return (unsigned)f2bf(a) | ((unsigned)f2bf(b) << 16);
}
union F4 { float4 v; float a[4]; };

// width-16 async global->LDS copy. LDS dest = wave-uniform base + lane*16;
// global src is per-lane. Fire-and-forget (vmcnt domain only). aux=0 only.
#define GLDS16(src, dst) __builtin_amdgcn_global_load_lds(                 \
    (const __attribute__((address_space(1))) unsigned int*)(src),          \
    (__attribute__((address_space(3))) unsigned int*)(dst), 16, 0, 0)

// ---------------------------------------------------------------------------
// KV pre-pack (unchanged, verified r1-r9): fp32 K,V -> bf16 swizzled 16KB
// tile images in workspace. One block per (k-tile, batch).
// ---------------------------------------------------------------------------
__global__ __launch_bounds__(256)
void prepack_kernel(const float* __restrict__ K, const float* __restrict__ V,
                    char* __restrict__ wsK, char* __restrict__ wsV) {
    __shared__ __align__(16) char smem[32768];
    char* Ks = smem;
    char* Vs = smem + 16384;
    const int t  = threadIdx.x;
    const int kt = blockIdx.x;
    const int b  = blockIdx.y;
    const float* Kg = K + (size_t)b * SS * DD;
    const float* Vg = V + (size_t)b * SS * DD;

    #pragma unroll
    for (int j = 0; j < 4; j++) {
        const int idx = 2 * t + 512 * j;
        const int row = idx >> 4;
        const int g   = (idx & 15) >> 1;
        const float* src = Kg + (size_t)(kt * 128) * DD + (size_t)idx * 4;
        F4 fa, fb; fa.v = *(const float4*)src; fb.v = *(const float4*)(src + 4);
        ushort8 u;
        #pragma unroll
        for (int e = 0; e < 4; e++) { u[e] = f2bf(fa.a[e]); u[e + 4] = f2bf(fb.a[e]); }
        *(ushort8*)(Ks + row * 128 + ((g ^ (row & 7)) * 16)) = u;
    }
    {
        const int d0v = (t & 15) * 4;
        const int kkb = (t >> 4) * 4;
        #pragma unroll
        for (int it2 = 0; it2 < 2; it2++) {
            const int kk = kkb + 64 * it2;
            const float* src = Vg + (size_t)(kt * 128 + kk) * DD + d0v;
            F4 r0, r1, r2, r3;
            r0.v = *(const float4*)(src);
            r1.v = *(const float4*)(src + DD);
            r2.v = *(const float4*)(src + 2 * DD);
            r3.v = *(const float4*)(src + 3 * DD);
            #pragma unroll
            for (int e = 0; e < 4; e++) {
                const int d = d0v + e;
                const uint2 wv = make_uint2(pk2(r0.a[e], r1.a[e]), pk2(r2.a[e], r3.a[e]));
                *(uint2*)(Vs + d * 256 + (((kk >> 3) ^ (d & 15)) * 16) + (kk & 7) * 2) = wv;
            }
        }
    }
    __syncthreads();
    char* dK = wsK + (size_t)(b * NT_TILES + kt) * TILE_BYTES;
    char* dV = wsV + (size_t)(b * NT_TILES + kt) * TILE_BYTES;
    #pragma unroll
    for (int j = 0; j < 4; j++) {
        *(float4*)(dK + t * 16 + j * 4096) = *(const float4*)(Ks + t * 16 + j * 4096);
        *(float4*)(dV + t * 16 + j * 4096) = *(const float4*)(Vs + t * 16 + j * 4096);
    }
}

// ---------------------------------------------------------------------------
// Main kernel (r8 structure, best-measured: 8 waves = 2 qs x 4 kh, shared KV
// dbuf + private M tbuf, counted vmcnt(4) + raw s_barrier lockstep, zero
// drains, V bank swizzle). Single rider vs r8 (clean A/B): bijective
// XCD-chunked block swizzle (T1, 512 = 8 x 64). r9 diagnosis: r2's
// FETCH=356MB vs 276MB mandatory = ~80MB KV re-reads leaking past L3 because
// round-robin dispatch puts all 16 batches' KV (8MB) on each 4MB XCD-L2.
// With the swizzle, XCD x serves ONE batch per round -> 512KB KV resident in
// its own L2; the mask stream per XCD is one contiguous ~16.7MB region.
// (r11 retry: byte-identical resubmit; prior two failures attributed to
// harness infra — this build has no unverified encodings.)
// ---------------------------------------------------------------------------
__global__ __launch_bounds__(512, 1)
void sdpa_mfma_kernel(const float* __restrict__ Q, const char* __restrict__ wsK,
                      const char* __restrict__ wsV, const unsigned int* __restrict__ M,
                      float* __restrict__ O) {
    __shared__ __align__(16) char smem[2 * KVBUF + 3 * MBUF];   // 160 KB exactly
    char* Qs = smem;                         // 8 KB, pre-loop only (in KV buf0)
    char* const Mbase = smem + 2 * KVBUF;    // M buffers
    float* red  = (float*)smem;              // epilogue partials (48 KB)
    float* denx = (float*)(smem + 49152);    // epilogue den exchange (1 KB)

    const int t    = threadIdx.x;
    const int lane = t & 63;
    const int l31  = lane & 31;
    const int half = lane >> 5;
    const int w    = t >> 6;          // wave id 0..7
    const int kh   = w & 3;           // k-chunk 32*kh of the 128-tile
    const int qs   = w >> 2;          // q-subtile (0: rows q0.., 1: rows q0+32..)

    // XCD-chunked bijective swizzle (T1): flat 0..511, 8 XCDs x 64 chunks.
    // nf = (flat%8)*64 + flat/8 is a bijection on [0,512) since 512 = 8*64.
    const int flat = blockIdx.y * (SS / 64) + blockIdx.x;
    const int nf   = (flat & 7) * 64 + (flat >> 3);
    const int b    = nf >> 5;
    const int q0   = (nf & 31) * 64;
    const int q0v  = q0 + 32 * qs;

    // ---- stage Q (64 rows, pre-scaled by 1/temperature), swizzled bf16 ----
    {
        const int sr = t >> 3, sc = t & 7;   // 512 thr -> 64 rows x 8 chunks
        const float* src = Q + ((size_t)b * SS + q0 + sr) * DD + sc * 8;
        F4 f0, f1; f0.v = *(const float4*)src; f1.v = *(const float4*)(src + 4);
        ushort8 u;
        #pragma unroll
        for (int e = 0; e < 4; e++) {
            u[e]     = f2bf(f0.a[e] * 0.125f);
            u[e + 4] = f2bf(f1.a[e] * 0.125f);
        }
        *(ushort8*)(Qs + sr * 128 + ((sc ^ (sr & 7)) * 16)) = u;
    }
    __syncthreads();

    const int qrow = l31;
    const int r7   = l31 & 7;
    bf16x8 bq[4];
    #pragma unroll
    for (int dc = 0; dc < 4; dc++)
        bq[dc] = __builtin_bit_cast(bf16x8, *(const ushort8*)(
            Qs + (32 * qs + qrow) * 128 + (((2 * dc + half) ^ r7) * 16)));
    __syncthreads();   // all bq reads done before prologue stages overwrite Qs

    f32x16 On0, On1;
    #pragma unroll
    for (int i = 0; i < 16; i++) { On0[i] = 0.f; On1[i] = 0.f; }
    float den0 = 0.f, den1 = 0.f;

    const char* tKbase = wsK + (size_t)b * NT_TILES * TILE_BYTES;
    const char* tVbase = wsV + (size_t)b * NT_TILES * TILE_BYTES;

    // mask staging src (r5-r8 verified): instr j covers rows q0v+8j+(lane>>3),
    // 16B chunk at col 32kh + 4*((lane&7)^(lane>>3)) (inverse swizzle)
    const unsigned int* Msrc = M + (size_t)b * SS * SS
                                 + (size_t)(q0v + (lane >> 3)) * SS
                                 + 32 * kh + 4 * ((lane & 7) ^ (lane >> 3));
    // V staging src per-lane offset (r6 granule extract + r8 bank swizzle)
    const int voff = ((lane >> 2) * 256)
                   + ((kh ^ ((lane >> 4) & 3)) * 64)
                   + ((((lane & 3) ^ ((lane >> 3) & 3) ^ ((lane >> 2) & 3)) * 16));

    auto stage_kv = [&](int bufn, int kt) {
        char* kvb = smem + bufn * KVBUF;
        if (qs == 0) {      // wave-uniform branch: qs=0 waves stage K slice kh
            const char* tK = tKbase + (size_t)kt * TILE_BYTES + 32 * kh * 128;
            #pragma unroll
            for (int j = 0; j < 4; j++)
                GLDS16(tK + j * 1024 + lane * 16, kvb + kh * 4096 + j * 1024);
        } else {            // qs=1 waves stage V slice kh (granule extract)
            const char* tV = tVbase + (size_t)kt * TILE_BYTES;
            #pragma unroll
            for (int j = 0; j < 4; j++)
                GLDS16(tV + j * 4096 + voff, kvb + 16384 + kh * 4096 + j * 1024);
        }
    };
    auto stage_m = [&](int bufn, int kt) {
        char* mb = Mbase + bufn * MBUF + w * 4096;
        const unsigned int* ms = Msrc + (size_t)kt * 128;
        #pragma unroll
        for (int j = 0; j < 4; j++)
            GLDS16(ms + (size_t)j * 8 * SS, mb + j * 1024);
    };

    // prologue: KV(0), M(0), M(1) in flight (12 glds)
    stage_kv(0, 0);
    stage_m(0, 0);
    stage_m(1, 1);

    #pragma unroll 1
    for (int kt = 0; kt < NT_TILES; ++kt) {
        // 1. counted wait: newest 4 = next M batch; retires M(kt) + KV(kt).
        asm volatile("s_waitcnt vmcnt(4)" ::: "memory");
        __builtin_amdgcn_sched_barrier(0);
        // 2. raw barrier (no drain): kt data visible cross-wave, kt-1 bufs free
        __builtin_amdgcn_s_barrier();
        // 3./4. stages (dead clamped tails target non-live buffers)
        const int kKV = (kt + 1 < NT_TILES) ? kt + 1 : NT_TILES - 1;
        const int kM  = (kt + 2 < NT_TILES) ? kt + 2 : NT_TILES - 1;
        stage_kv((kt + 1) & 1, kKV);
        stage_m((kt + 2) % 3, kM);

        // 5. consume tile kt
        const char* kvb = smem + (kt & 1) * KVBUF;
        const char* mb  = Mbase + (kt % 3) * MBUF + w * 4096;

        bf16x8 ak[4];
        #pragma unroll
        for (int dc = 0; dc < 4; dc++)
            ak[dc] = __builtin_bit_cast(bf16x8, *(const ushort8*)(
                kvb + kh * 4096 + l31 * 128 + (((2 * dc + half) ^ r7) * 16)));
        uint4v mt[4];
        #pragma unroll
        for (int g = 0; g < 4; g++)
            mt[g] = *(const uint4v*)(mb + l31 * 128 + 16 * ((half + 2 * g) ^ r7));
        bf16x8 av[2][2];
        #pragma unroll
        for (int s2 = 0; s2 < 2; s2++)
            #pragma unroll
            for (int dc = 0; dc < 2; dc++) {
                const int vrow = 32 * dc + l31;
                av[s2][dc] = __builtin_bit_cast(bf16x8, *(const ushort8*)(
                    kvb + 16384 + kh * 4096 + vrow * 64 +
                    (((2 * s2 + half) ^ ((l31 >> 1) & 3)) * 16)));
            }

        // QK^T: S^T tile [32k x 32q]
        f32x16 S;
        #pragma unroll
        for (int i = 0; i < 16; i++) S[i] = 0.f;
        #pragma unroll
        for (int dc = 0; dc < 4; dc++)
            S = __builtin_amdgcn_mfma_f32_32x32x16_bf16(ak[dc], bq[dc], S, 0, 0, 0);

        // mask + exp + denominator (C row = e + 8g + 4half)
        float p[16];
        #pragma unroll
        for (int g = 0; g < 4; g++) {
            #pragma unroll
            for (int e = 0; e < 4; e++) {
                const float ev = __expf(S[4 * g + e]);
                const float pv = mt[g][e] ? 1.0f : ev;
                p[4 * g + e] = pv;
                if (g & 1) den1 += pv; else den0 += pv;
            }
        }

        // P*V: B-operand frags via shfl_xor(32), 2 ksubs (r0-proven)
        #pragma unroll
        for (int s2 = 0; s2 < 2; s2++) {
            const unsigned o0 = pk2(p[8 * s2 + 0], p[8 * s2 + 1]);
            const unsigned o1 = pk2(p[8 * s2 + 2], p[8 * s2 + 3]);
            const unsigned o2 = pk2(p[8 * s2 + 4], p[8 * s2 + 5]);
            const unsigned o3 = pk2(p[8 * s2 + 6], p[8 * s2 + 7]);
            const unsigned s0 = half ? o0 : o2;
            const unsigned s1 = half ? o1 : o3;
            const unsigned r0 = (unsigned)__shfl_xor((int)s0, 32, 64);
            const unsigned r1 = (unsigned)__shfl_xor((int)s1, 32, 64);
            uint4 bu;
            bu.x = half ? r0 : o0;
            bu.y = half ? r1 : o1;
            bu.z = half ? o2 : r0;
            bu.w = half ? o3 : r1;
            const bf16x8 bp = __builtin_bit_cast(bf16x8, bu);
            On0 = __builtin_amdgcn_mfma_f32_32x32x16_bf16(av[s2][0], bp, On0, 0, 0, 0);
            On1 = __builtin_amdgcn_mfma_f32_32x32x16_bf16(av[s2][1], bp, On1, 0, 0, 0);
        }
    }

    // ---- epilogue: lane halves, then 4-way kh reduction per qs group ----
    const float den_acc = den0 + den1;
    const float den_tot = den_acc + __shfl_xor(den_acc, 32, 64);

    __syncthreads();   // full drain (incl. dead tail stages); bufs -> red/denx
    if (kh != 0) {
        #pragma unroll
        for (int dc = 0; dc < 2; dc++)
            #pragma unroll
            for (int g = 0; g < 4; g++) {
                const f32x16& Oc = dc ? On1 : On0;
                float4 st;
                st.x = Oc[4 * g + 0]; st.y = Oc[4 * g + 1];
                st.z = Oc[4 * g + 2]; st.w = Oc[4 * g + 3];
                *(float4*)((char*)red + qs * 24576 + (kh - 1) * 8192 +
                           (dc * 4 + g) * 1024 + lane * 16) = st;
            }
        if (lane < 32) denx[w * 32 + l31] = den_tot;
    }
    __syncthreads();
    if (kh == 0) {
        const float inv = 1.0f / (den_tot + denx[(qs * 4 + 1) * 32 + l31]
                                          + denx[(qs * 4 + 2) * 32 + l31]
                                          + denx[(qs * 4 + 3) * 32 + l31]);
        float* Og = O + ((size_t)b * SS + q0v + qrow) * DD;
        #pragma unroll
        for (int dc = 0; dc < 2; dc++)
            #pragma unroll
            for (int g = 0; g < 4; g++) {
                const f32x16& Oc = dc ? On1 : On0;
                float4 st;
                st.x = Oc[4 * g + 0]; st.y = Oc[4 * g + 1];
                st.z = Oc[4 * g + 2]; st.w = Oc[4 * g + 3];
                #pragma unroll
                for (int w2 = 0; w2 < 3; w2++) {
                    const float4 pr = *(const float4*)((char*)red + qs * 24576 +
                                        w2 * 8192 + (dc * 4 + g) * 1024 + lane * 16);
                    st.x += pr.x; st.y += pr.y; st.z += pr.z; st.w += pr.w;
                }
                st.x *= inv; st.y *= inv; st.z *= inv; st.w *= inv;
                // d = e + 8g + 4half + 32dc  (C-row formula)
                *(float4*)(Og + 32 * dc + 8 * g + 4 * half) = st;
            }
    }
}

extern "C" void kernel_launch(void* const* d_in, const int* in_sizes, int n_in,
                              void* d_out, int out_size, void* d_ws, size_t ws_size,
                              hipStream_t stream) {
    const float* q = (const float*)d_in[0];
    const float* k = (const float*)d_in[1];
    const float* v = (const float*)d_in[2];
    const unsigned int* m = (const unsigned int*)d_in[3];
    float* out = (float*)d_out;

    // workspace: 4 MB K images + 4 MB V images (bf16, swizzled tile layout)
    char* wsK = (char*)d_ws;
    char* wsV = wsK + (size_t)BB * NT_TILES * TILE_BYTES;

    dim3 pgrid(NT_TILES, BB);           // 256 blocks
    prepack_kernel<<<pgrid, 256, 0, stream>>>(k, v, wsK, wsV);

    dim3 grid(SS / 64, BB);             // 512 blocks x 512 thr -> 1/CU, 2 rounds
    sdpa_mfma_kernel<<<grid, 512, 0, stream>>>(q, wsK, wsV, m, out);
}